// Round 1
// baseline (367.535 us; speedup 1.0000x reference)
//
#include <hip/hip_runtime.h>

#define NB 2
#define NS 2048
#define NH 32
#define NKV 8
#define ND 128
#define NWIN 1024
#define FSCALE 0.08838834764831845f

typedef __bf16 bf16x8 __attribute__((ext_vector_type(8)));
typedef float f32x4 __attribute__((ext_vector_type(4)));
typedef unsigned short u16x4 __attribute__((ext_vector_type(4)));
typedef unsigned short u16x8 __attribute__((ext_vector_type(8)));

union Frag { u16x8 u; bf16x8 b; };

__device__ __forceinline__ unsigned short f2bf(float x) {
  union { float f; unsigned int i; } a; a.f = x;
  unsigned int r = a.i + 0x7FFFu + ((a.i >> 16) & 1u);
  return (unsigned short)(r >> 16);
}

// Block: 256 threads = 4 waves. Block handles one (b, h, 64-row q-tile).
// Wave w handles q rows [q0 + 16w, q0 + 16w + 16).
// KV iterated in tiles of 32 keys, staged fp32->bf16 in LDS.
// MFMA 16x16x32 bf16:
//   A frag: lane holds A[l&15][(l>>4)*8 + j], j=0..7
//   B frag: lane holds B[(l>>4)*8 + j][l&15]
//   C/D   : lane holds C[(l>>4)*4 + r][l&15], r=0..3   (m89-verified)
__global__ __launch_bounds__(256, 2)
void attn_fwd(const float* __restrict__ qg, const float* __restrict__ kg,
              const float* __restrict__ vg, float* __restrict__ og) {
  __shared__ unsigned short k_lds[32 * 128];      // swizzled rows of 256B
  __shared__ unsigned short v_lds[32 * 132];      // padded rows (+4 bf16)
  __shared__ unsigned short p_lds[4][16 * 64];    // per-wave P, 128B rows, swizzled

  const int tid = threadIdx.x;
  const int w = tid >> 6;
  const int lane = tid & 63;
  const int l15 = lane & 15;
  const int lg = lane >> 4;

  const int bid = blockIdx.x;
  const int qt = bid & 31;          // 32 q-tiles
  const int h = (bid >> 5) & 31;    // 32 heads
  const int b = bid >> 10;          // 2 batches
  const int hkv = h >> 2;           // GQA group of 4
  const float slope = exp2f(-0.25f * (float)(h + 1));

  const int q0 = qt * 64;

  // ---- load Q fragments (fp32 -> bf16, 4 K-steps over D=128) ----
  u16x8 qf[4];
  {
    const int qrow = q0 + w * 16 + l15;
    const float* qp = qg + (size_t)(b * NS + qrow) * (NH * ND) + h * ND;
#pragma unroll
    for (int ks = 0; ks < 4; ++ks) {
      const int dbase = ks * 32 + lg * 8;
      float4 f0 = *(const float4*)(qp + dbase);
      float4 f1 = *(const float4*)(qp + dbase + 4);
      u16x8 u;
      u[0] = f2bf(f0.x); u[1] = f2bf(f0.y); u[2] = f2bf(f0.z); u[3] = f2bf(f0.w);
      u[4] = f2bf(f1.x); u[5] = f2bf(f1.y); u[6] = f2bf(f1.z); u[7] = f2bf(f1.w);
      qf[ks] = u;
    }
  }

  float m_i[4], l_i[4];
  f32x4 acc[8];
#pragma unroll
  for (int i = 0; i < 4; ++i) { m_i[i] = -1e30f; l_i[i] = 0.f; }
#pragma unroll
  for (int c = 0; c < 8; ++c) {
    acc[c][0] = 0.f; acc[c][1] = 0.f; acc[c][2] = 0.f; acc[c][3] = 0.f;
  }

  const int t0 = (q0 >= NWIN) ? ((q0 - NWIN) >> 5) : 0;
  const int t1 = (q0 + 63) >> 5;

  for (int t = t0; t <= t1; ++t) {
    const int kvbase = t * 32;
    __syncthreads();  // prior iteration's LDS reads complete before overwrite
    // ---- stage K, V tiles (32 rows x 128, fp32 -> bf16) ----
#pragma unroll
    for (int it = 0; it < 4; ++it) {
      const int row = it * 8 + (tid >> 5);
      const int dbase = (tid & 31) * 4;
      const size_t go = (size_t)(b * NS + kvbase + row) * (NKV * ND) + hkv * ND + dbase;
      float4 kf = *(const float4*)(kg + go);
      float4 vf = *(const float4*)(vg + go);
      u16x4 ku, vu;
      ku[0] = f2bf(kf.x); ku[1] = f2bf(kf.y); ku[2] = f2bf(kf.z); ku[3] = f2bf(kf.w);
      vu[0] = f2bf(vf.x); vu[1] = f2bf(vf.y); vu[2] = f2bf(vf.z); vu[3] = f2bf(vf.w);
      const int kb = (row * 256 + dbase * 2) ^ ((row & 7) << 4);
      *(u16x4*)((char*)k_lds + kb) = ku;
      *(u16x4*)(&v_lds[row * 132 + dbase]) = vu;
    }
    __syncthreads();

    // ---- QK^T: S[16 q][32 k] as two 16x16 C-frags ----
    f32x4 s0 = {0.f, 0.f, 0.f, 0.f};
    f32x4 s1 = {0.f, 0.f, 0.f, 0.f};
#pragma unroll
    for (int ks = 0; ks < 4; ++ks) {
      const int db2 = (ks * 32 + lg * 8) * 2;
      const int xo = (l15 & 7) << 4;
      Frag kb0, kb1, qa;
      kb0.u = *(u16x8*)((char*)k_lds + ((l15 * 256 + db2) ^ xo));
      kb1.u = *(u16x8*)((char*)k_lds + (((l15 + 16) * 256 + db2) ^ xo));
      qa.u = qf[ks];
      s0 = __builtin_amdgcn_mfma_f32_16x16x32_bf16(qa.b, kb0.b, s0, 0, 0, 0);
      s1 = __builtin_amdgcn_mfma_f32_16x16x32_bf16(qa.b, kb1.b, s1, 0, 0, 0);
    }

    // ---- online softmax (4 rows per lane; row = lg*4 + i, col = l15) ----
    const int j0 = kvbase + l15;
    const int j1 = j0 + 16;
#pragma unroll
    for (int i = 0; i < 4; ++i) {
      const int qi = q0 + w * 16 + lg * 4 + i;
      float sv0 = s0[i] * FSCALE - slope * (float)(qi - j0);
      float sv1 = s1[i] * FSCALE - slope * (float)(qi - j1);
      if (!(j0 <= qi && j0 + NWIN >= qi)) sv0 = -1e30f;  // causal + window
      if (!(j1 <= qi && j1 + NWIN >= qi)) sv1 = -1e30f;
      float tm = fmaxf(sv0, sv1);
#pragma unroll
      for (int msk = 1; msk <= 8; msk <<= 1) tm = fmaxf(tm, __shfl_xor(tm, msk, 64));
      const float newm = fmaxf(m_i[i], tm);
      // -1e30 sentinel: fully-masked leading tiles give fac=exp(0)=1, p=1
      // (garbage), which is wiped by fac=exp(-1e30-m)=0 at the first real tile.
      const float fac = __expf(m_i[i] - newm);
      const float p0 = __expf(sv0 - newm);
      const float p1 = __expf(sv1 - newm);
      float rs = p0 + p1;
#pragma unroll
      for (int msk = 1; msk <= 8; msk <<= 1) rs += __shfl_xor(rs, msk, 64);
      l_i[i] = l_i[i] * fac + rs;
      m_i[i] = newm;
#pragma unroll
      for (int c = 0; c < 8; ++c) acc[c][i] *= fac;
      // transpose P through per-wave LDS into PV A-fragment layout
      const int prow = lg * 4 + i;
      const int pxo = (prow & 7) << 4;
      *(unsigned short*)((char*)p_lds[w] + ((prow * 128 + l15 * 2) ^ pxo)) = f2bf(p0);
      *(unsigned short*)((char*)p_lds[w] + ((prow * 128 + (l15 + 16) * 2) ^ pxo)) = f2bf(p1);
    }

    // ---- PV: O[16 q][128] += P[16][32] * V[32][128] ----
    Frag pa;
    pa.u = *(u16x8*)((char*)p_lds[w] + ((l15 * 128 + lg * 16) ^ ((l15 & 7) << 4)));
#pragma unroll
    for (int c = 0; c < 8; ++c) {
      Frag vb;
#pragma unroll
      for (int j = 0; j < 8; ++j) {
        vb.u[j] = v_lds[(lg * 8 + j) * 132 + c * 16 + l15];
      }
      acc[c] = __builtin_amdgcn_mfma_f32_16x16x32_bf16(pa.b, vb.b, acc[c], 0, 0, 0);
    }
  }

  // ---- epilogue: O = acc / l ----
#pragma unroll
  for (int i = 0; i < 4; ++i) {
    const int qi = q0 + w * 16 + lg * 4 + i;
    const float inv = 1.0f / l_i[i];
    float* op = og + (size_t)(b * NS + qi) * (NH * ND) + h * ND;
#pragma unroll
    for (int c = 0; c < 8; ++c) op[c * 16 + l15] = acc[c][i] * inv;
  }
}

extern "C" void kernel_launch(void* const* d_in, const int* in_sizes, int n_in,
                              void* d_out, int out_size, void* d_ws, size_t ws_size,
                              hipStream_t stream) {
  (void)in_sizes; (void)n_in; (void)d_ws; (void)ws_size; (void)out_size;
  const float* q = (const float*)d_in[0];
  const float* k = (const float*)d_in[1];
  const float* v = (const float*)d_in[2];
  float* out = (float*)d_out;
  dim3 grid(NB * NH * (NS / 64));
  dim3 block(256);
  attn_fwd<<<grid, block, 0, stream>>>(q, k, v, out);
}

// Round 3
// 224.026 us; speedup vs baseline: 1.6406x; 1.6406x over previous
//
#include <hip/hip_runtime.h>
#include <stdint.h>

#define NB 2
#define NS 2048
#define NH 32
#define NKV 8
#define ND 128
#define NWIN 1024
#define FSCALE 0.08838834764831845f

typedef __bf16 bf16x8 __attribute__((ext_vector_type(8)));
typedef float f32x4 __attribute__((ext_vector_type(4)));
typedef unsigned short u16x4 __attribute__((ext_vector_type(4)));
typedef unsigned short u16x8 __attribute__((ext_vector_type(8)));
typedef unsigned int u32x2 __attribute__((ext_vector_type(2)));

union Frag { u16x8 u; bf16x8 b; u32x2 w[2]; };
union BF4 { u16x4 u; __bf16 b[4]; };
union BF1 { unsigned short u; __bf16 b; };

// Block: 256 threads = 4 waves; block = (b, h, 64-row q-tile); wave w owns 16 q-rows.
// KV tiles of 64 keys. Async reg-staged double buffer: loads for tile t+1 issue
// right after the post-staging barrier; fp32->bf16 convert+LDS-write happens at
// the top of iteration t+1 (HBM latency hides under tile t's compute).
// K in LDS: row-major 256B rows, XOR-swizzled (byte ^= (row&7)<<4).
// V in LDS: tr-subtiled for ds_read_b64_tr_b16:
//   elem V[k][d] at  (d>>4)*1024 + s*256 + g*64 + j*16 + (d&15)
//   with s = (k>>5)*2 | ((k>>2)&1), g = (k>>3)&3, j = k&3.
// tr-read semantics (m156/m162): PER-LANE addr_l; each lane fetches 8B at its
// own addr; within each 16-lane group the 16x4 elems transpose so dst lane l,
// elem j = lds_elem[win_base/2 + (l>>4)*64 + j*16 + (l&15)] when
// addr_l = base + l*8 (uniform-base was Round-2's bug: broadcast, not transpose).
// Read r at byte base + c*2048 + r*512 gives lane l elem j:
//   V[32*(r>>1) + 8*(l>>4) + 4*(r&1) + j][c*16 + (l&15)]  == PV B-fragment rows.
__global__ __launch_bounds__(256, 2)
void attn_fwd(const float* __restrict__ qg, const float* __restrict__ kg,
              const float* __restrict__ vg, float* __restrict__ og) {
  __shared__ unsigned short k_lds[64 * 128];     // 16 KB
  __shared__ unsigned short v_lds[64 * 128];     // 16 KB
  __shared__ unsigned short p_lds[4][16 * 64];   // 8 KB, per-wave P

  const int tid = threadIdx.x;
  const int w = tid >> 6;
  const int lane = tid & 63;
  const int l15 = lane & 15;
  const int lg = lane >> 4;

  const int bid = blockIdx.x;
  const int h = bid & 31;           // h fastest: GQA group shares K/V in L2
  const int qt = (bid >> 5) & 31;
  const int b = bid >> 10;
  const int hkv = h >> 2;
  const float slope = exp2f(-0.25f * (float)(h + 1));
  const int q0 = qt * 64;

  // ---- Q fragments (fp32 -> bf16), 4 K-steps over D=128 ----
  u16x8 qf[4];
  {
    const int qrow = q0 + w * 16 + l15;
    const float* qp = qg + (size_t)(b * NS + qrow) * (NH * ND) + h * ND;
#pragma unroll
    for (int ks = 0; ks < 4; ++ks) {
      const int dbase = ks * 32 + lg * 8;
      float4 f0 = *(const float4*)(qp + dbase);
      float4 f1 = *(const float4*)(qp + dbase + 4);
      Frag q_;
      q_.b[0] = (__bf16)f0.x; q_.b[1] = (__bf16)f0.y;
      q_.b[2] = (__bf16)f0.z; q_.b[3] = (__bf16)f0.w;
      q_.b[4] = (__bf16)f1.x; q_.b[5] = (__bf16)f1.y;
      q_.b[6] = (__bf16)f1.z; q_.b[7] = (__bf16)f1.w;
      qf[ks] = q_.u;
    }
  }

  float m_i[4], l_i[4];
  f32x4 acc[8];
#pragma unroll
  for (int i = 0; i < 4; ++i) { m_i[i] = -1e30f; l_i[i] = 0.f; }
#pragma unroll
  for (int c = 0; c < 8; ++c) {
    acc[c][0] = 0.f; acc[c][1] = 0.f; acc[c][2] = 0.f; acc[c][3] = 0.f;
  }

  const int srow = tid >> 5;        // 0..7
  const int sdb = (tid & 31) * 4;   // 0..124
  const int sc = sdb >> 4;
  const int sx = sdb & 15;
  float4 kreg[8], vreg[8];

  const int t0 = (q0 >= NWIN) ? ((q0 - NWIN) >> 6) : 0;
  const int t1 = q0 >> 6;           // q0 % 64 == 0

  auto load_tile = [&](int t) {
    const int kvbase = t * 64;
#pragma unroll
    for (int it = 0; it < 8; ++it) {
      const size_t go =
          (size_t)(b * NS + kvbase + it * 8 + srow) * (NKV * ND) + hkv * ND + sdb;
      kreg[it] = *(const float4*)(kg + go);
      vreg[it] = *(const float4*)(vg + go);
    }
  };

  load_tile(t0);

  for (int t = t0; t <= t1; ++t) {
    const int kvbase = t * 64;
    __syncthreads();   // prior tile's LDS reads complete before overwrite
    // ---- convert + write staged regs to LDS ----
#pragma unroll
    for (int it = 0; it < 8; ++it) {
      const int row = it * 8 + srow;
      BF4 ku, vu;
      ku.b[0] = (__bf16)kreg[it].x; ku.b[1] = (__bf16)kreg[it].y;
      ku.b[2] = (__bf16)kreg[it].z; ku.b[3] = (__bf16)kreg[it].w;
      vu.b[0] = (__bf16)vreg[it].x; vu.b[1] = (__bf16)vreg[it].y;
      vu.b[2] = (__bf16)vreg[it].z; vu.b[3] = (__bf16)vreg[it].w;
      const int kb = (row * 256 + sdb * 2) ^ ((row & 7) << 4);
      *(u16x4*)((char*)k_lds + kb) = ku.u;
      const int s2 = ((row >> 5) << 1) | ((row >> 2) & 1);
      const int vi = sc * 1024 + s2 * 256 + ((row >> 3) & 3) * 64 + (row & 3) * 16 + sx;
      *(u16x4*)(&v_lds[vi]) = vu.u;
    }
    __syncthreads();
    if (t < t1) load_tile(t + 1);   // async prefetch; first use is next iter's convert

    // ---- QK^T: S[16 q][64 k] as four 16x16 C-frags ----
    f32x4 s[4];
#pragma unroll
    for (int f = 0; f < 4; ++f) { s[f][0] = 0.f; s[f][1] = 0.f; s[f][2] = 0.f; s[f][3] = 0.f; }
    const int xo = (l15 & 7) << 4;
#pragma unroll
    for (int ks = 0; ks < 4; ++ks) {
      const int db2 = ks * 64 + lg * 16;
      Frag qa; qa.u = qf[ks];
#pragma unroll
      for (int f = 0; f < 4; ++f) {
        Frag kb;
        kb.u = *(u16x8*)((char*)k_lds + (((f * 16 + l15) * 256 + db2) ^ xo));
        s[f] = __builtin_amdgcn_mfma_f32_16x16x32_bf16(qa.b, kb.b, s[f], 0, 0, 0);
      }
    }

    // ---- online softmax; rows = lg*4 + i, frag cols = f*16 + l15 ----
#pragma unroll
    for (int i = 0; i < 4; ++i) {
      const int qi = q0 + w * 16 + lg * 4 + i;
      const int prow = lg * 4 + i;
      const int pxo = (prow & 7) << 4;
      float sv[4];
#pragma unroll
      for (int f = 0; f < 4; ++f) {
        const int j = kvbase + f * 16 + l15;
        const float val = fmaf(s[f][i], FSCALE, -slope * (float)(qi - j));
        sv[f] = (j <= qi && j + NWIN >= qi) ? val : -1e30f;
      }
      float tm = fmaxf(fmaxf(sv[0], sv[1]), fmaxf(sv[2], sv[3]));
#pragma unroll
      for (int msk = 1; msk <= 8; msk <<= 1) tm = fmaxf(tm, __shfl_xor(tm, msk, 64));
      const float newm = fmaxf(m_i[i], tm);
      // -1e30 sentinel: garbage from fully-masked leading rows is wiped by fac=0
      // at the first real tile (acc starts at 0).
      const float fac = __expf(m_i[i] - newm);
      float rs = 0.f;
#pragma unroll
      for (int f = 0; f < 4; ++f) {
        const float p = __expf(sv[f] - newm);
        rs += p;
        BF1 pb; pb.b = (__bf16)p;
        *(unsigned short*)((char*)p_lds[w] +
            ((prow * 128 + (f * 16 + l15) * 2) ^ pxo)) = pb.u;
      }
#pragma unroll
      for (int msk = 1; msk <= 8; msk <<= 1) rs += __shfl_xor(rs, msk, 64);
      l_i[i] = l_i[i] * fac + rs;
      m_i[i] = newm;
#pragma unroll
      for (int c = 0; c < 8; ++c) acc[c][i] *= fac;
    }

    // ---- PV: O[16 q][128] += P[16][64] * V[64][128] ----
    Frag pa[2];
#pragma unroll
    for (int ks = 0; ks < 2; ++ks) {
      pa[ks].u = *(u16x8*)((char*)p_lds[w] +
          ((l15 * 128 + (ks * 32 + lg * 8) * 2) ^ ((l15 & 7) << 4)));
    }
    // PER-LANE tr-read address (Round-2 fix): lane*8 within each 512B window.
    const unsigned int vbase = (unsigned int)(uintptr_t)(&v_lds[0]) + lane * 8;
#pragma unroll
    for (int c = 0; c < 8; ++c) {
      u32x2 r0, r1, r2, r3;
      const unsigned int a = vbase + c * 2048;
      asm volatile("ds_read_b64_tr_b16 %0, %1" : "=v"(r0) : "v"(a));
      asm volatile("ds_read_b64_tr_b16 %0, %1 offset:512" : "=v"(r1) : "v"(a));
      asm volatile("ds_read_b64_tr_b16 %0, %1 offset:1024" : "=v"(r2) : "v"(a));
      asm volatile("ds_read_b64_tr_b16 %0, %1 offset:1536" : "=v"(r3) : "v"(a));
      asm volatile("s_waitcnt lgkmcnt(0)" ::: "memory");
      __builtin_amdgcn_sched_barrier(0);
      Frag vb0, vb1;
      vb0.w[0] = r0; vb0.w[1] = r1;   // ks=0: k rows 8lg..8lg+3, 8lg+4..8lg+7
      vb1.w[0] = r2; vb1.w[1] = r3;   // ks=1: +32
      acc[c] = __builtin_amdgcn_mfma_f32_16x16x32_bf16(pa[0].b, vb0.b, acc[c], 0, 0, 0);
      acc[c] = __builtin_amdgcn_mfma_f32_16x16x32_bf16(pa[1].b, vb1.b, acc[c], 0, 0, 0);
    }
  }

  // ---- epilogue: O = acc / l ----
#pragma unroll
  for (int i = 0; i < 4; ++i) {
    const int qi = q0 + w * 16 + lg * 4 + i;
    const float inv = 1.0f / l_i[i];
    float* op = og + (size_t)(b * NS + qi) * (NH * ND) + h * ND;
#pragma unroll
    for (int c = 0; c < 8; ++c) op[c * 16 + l15] = acc[c][i] * inv;
  }
}

extern "C" void kernel_launch(void* const* d_in, const int* in_sizes, int n_in,
                              void* d_out, int out_size, void* d_ws, size_t ws_size,
                              hipStream_t stream) {
  (void)in_sizes; (void)n_in; (void)d_ws; (void)ws_size; (void)out_size;
  const float* q = (const float*)d_in[0];
  const float* k = (const float*)d_in[1];
  const float* v = (const float*)d_in[2];
  float* out = (float*)d_out;
  dim3 grid(NB * NH * (NS / 64));
  dim3 block(256);
  attn_fwd<<<grid, block, 0, stream>>>(q, k, v, out);
}